// Round 1
// baseline (408.274 us; speedup 1.0000x reference)
//
#include <hip/hip_runtime.h>

// ImportanceAggregator: out = LN( (sum_k w~[n,k] * feat[nbr[n,k]]) @ W + b ) * gamma + beta
// Key simplification: pooling commutes with the linear layer (sum of w~ == 1),
// so pool over K first (16x fewer matmul FLOPs than the reference dataflow).

#define NN   50000
#define KNB  16
#define D    256
#define TM   16    // nodes per block
#define KC   32    // W rows staged per LDS chunk

__global__ __launch_bounds__(256) void ia_fused(
    const float* __restrict__ feat,   // [NN, D]
    const int*   __restrict__ nbr,    // [NN, KNB]
    const float* __restrict__ iw,     // [NN, KNB]
    const float* __restrict__ Wm,     // [D, D] row-major: W[k][c]
    const float* __restrict__ bias,   // [D]
    const float* __restrict__ gamma,  // [D]
    const float* __restrict__ beta,   // [D]
    float* __restrict__ out)          // [NN, D]
{
    __shared__ float sPooled[TM][D];  // 16 KB
    __shared__ float sW[KC][D];       // 32 KB

    const int t    = threadIdx.x;
    const int lane = t & 63;
    const int wq   = t >> 6;          // wave id 0..3
    const int base = blockIdx.x * TM;

    // ---------------- Phase 1: weighted neighbor pooling -> sPooled ----------
    // Wave wq handles rows {mb+wq}; 64 lanes x float4 cover all 256 cols.
    for (int mb = 0; mb < TM; mb += 4) {
        const int  m = mb + wq;
        const long n = base + m;      // wave-uniform -> scalar loads for idx/w
        float w[KNB];
        float ws = 0.f;
        #pragma unroll
        for (int k = 0; k < KNB; ++k) { w[k] = iw[n * KNB + k]; ws += w[k]; }
        const bool  zs  = (ws == 0.f);
        const float inv = zs ? (1.f / KNB) : (1.f / ws);

        float4 p = make_float4(0.f, 0.f, 0.f, 0.f);
        #pragma unroll
        for (int k = 0; k < KNB; ++k) {
            const float wk  = zs ? inv : (w[k] * inv);
            const long  idx = nbr[n * KNB + k];
            const float4 f  = *(const float4*)(feat + idx * D + lane * 4);
            p.x += wk * f.x; p.y += wk * f.y; p.z += wk * f.z; p.w += wk * f.w;
        }
        *(float4*)&sPooled[m][lane * 4] = p;
    }

    // ---------------- Phase 2: GEMM  agg = pooled @ W  (4x4 register tile) ---
    const int r0 = wq * 4;            // rows r0..r0+3 (wave-uniform -> broadcast a-reads)
    const int c0 = lane * 4;          // cols c0..c0+3 (b128 conflict-free w-reads)
    float4 acc[4];
    #pragma unroll
    for (int j = 0; j < 4; ++j) acc[j] = make_float4(0.f, 0.f, 0.f, 0.f);

    for (int kb = 0; kb < D; kb += KC) {
        __syncthreads();  // phase-1 done (first iter) / previous chunk consumed
        {   // stage W[kb..kb+KC) x [0..D) into sW, float4-coalesced
            const float4* src = (const float4*)(Wm + (size_t)kb * D);
            float4*       dst = (float4*)&sW[0][0];
            #pragma unroll
            for (int i = 0; i < (KC * D / 4) / 256; ++i)
                dst[t + i * 256] = src[t + i * 256];
        }
        __syncthreads();
        #pragma unroll
        for (int k = 0; k < KC; k += 4) {
            const float4 w0 = *(const float4*)&sW[k + 0][c0];
            const float4 w1 = *(const float4*)&sW[k + 1][c0];
            const float4 w2 = *(const float4*)&sW[k + 2][c0];
            const float4 w3 = *(const float4*)&sW[k + 3][c0];
            #pragma unroll
            for (int j = 0; j < 4; ++j) {
                const float4 a = *(const float4*)&sPooled[r0 + j][kb + k];
                acc[j].x += a.x * w0.x + a.y * w1.x + a.z * w2.x + a.w * w3.x;
                acc[j].y += a.x * w0.y + a.y * w1.y + a.z * w2.y + a.w * w3.y;
                acc[j].z += a.x * w0.z + a.y * w1.z + a.z * w2.z + a.w * w3.z;
                acc[j].w += a.x * w0.w + a.y * w1.w + a.z * w2.w + a.w * w3.w;
            }
        }
    }

    // ---------------- Phase 3: +bias, LayerNorm, store -----------------------
    __syncthreads();  // all sPooled reads done; safe to overwrite with agg
    {
        const float4 bv = *(const float4*)&bias[c0];
        #pragma unroll
        for (int j = 0; j < 4; ++j) {
            float4 v = acc[j];
            v.x += bv.x; v.y += bv.y; v.z += bv.z; v.w += bv.w;
            *(float4*)&sPooled[r0 + j][c0] = v;
        }
    }
    __syncthreads();

    const float4 gv = *(const float4*)&gamma[lane * 4];
    const float4 bt = *(const float4*)&beta[lane * 4];
    #pragma unroll
    for (int j = 0; j < 4; ++j) {
        const int m = wq * 4 + j;     // wave wq normalizes rows wq*4..wq*4+3
        const float4 v = *(const float4*)&sPooled[m][lane * 4];
        float s  = v.x + v.y + v.z + v.w;
        float sq = v.x * v.x + v.y * v.y + v.z * v.z + v.w * v.w;
        #pragma unroll
        for (int off = 32; off; off >>= 1) {
            s  += __shfl_xor(s,  off, 64);
            sq += __shfl_xor(sq, off, 64);
        }
        const float mean = s * (1.f / D);
        const float var  = sq * (1.f / D) - mean * mean;   // biased, matches torch
        const float rstd = rsqrtf(var + 1e-5f);
        const long  n    = base + m;
        float4 o;
        o.x = (v.x - mean) * rstd * gv.x + bt.x;
        o.y = (v.y - mean) * rstd * gv.y + bt.y;
        o.z = (v.z - mean) * rstd * gv.z + bt.z;
        o.w = (v.w - mean) * rstd * gv.w + bt.w;
        *(float4*)(out + n * D + lane * 4) = o;
    }
}

extern "C" void kernel_launch(void* const* d_in, const int* in_sizes, int n_in,
                              void* d_out, int out_size, void* d_ws, size_t ws_size,
                              hipStream_t stream) {
    const float* feat  = (const float*)d_in[0];
    const int*   nbr   = (const int*)d_in[1];
    const float* iw    = (const float*)d_in[2];
    const float* Wm    = (const float*)d_in[3];
    const float* b     = (const float*)d_in[4];
    const float* g     = (const float*)d_in[5];
    const float* be    = (const float*)d_in[6];
    float*       out   = (float*)d_out;

    dim3 grid(NN / TM);   // 50000/16 = 3125 exactly, no tail
    ia_fused<<<grid, dim3(256), 0, stream>>>(feat, nbr, iw, Wm, b, g, be, out);
}

// Round 2
// 272.661 us; speedup vs baseline: 1.4974x; 1.4974x over previous
//
#include <hip/hip_runtime.h>

// ImportanceAggregator, split pipeline:
//   K0 convert_w : W[k][c] fp32 -> Wt[c][k] bf16 in d_ws (128 KB, L2-hot)
//   K1 pool      : agg[n] = sum_k w~[n,k] * feat[nbr[n,k]]  (fp32 acc, bf16 store)
//                  one WAVE per node, no LDS, no barriers -> max latency hiding
//   K2 gemm_ln   : out = LN(aggbf16 @ Wtbf16 + b) * gamma + beta  via MFMA 16x16x32
// agg bf16 rows live in d_out at 1 KB stride (row n bytes [n*1024, n*1024+512)),
// overwritten by the same block's final fp32 stores only after its reads complete.

#define NN   50000
#define KNB  16
#define D    256

typedef __attribute__((ext_vector_type(8))) short short8;   // 8 x bf16 (4 VGPRs)
typedef __attribute__((ext_vector_type(4))) float f32x4;

static __device__ __forceinline__ unsigned short f2bf(float x) {
    unsigned int u = __float_as_uint(x);
    return (unsigned short)((u + 0x7FFFu + ((u >> 16) & 1u)) >> 16);  // RNE
}

// ---------------- K0: W transpose + bf16 convert --------------------------
__global__ __launch_bounds__(256) void convert_w(const float* __restrict__ Wm,
                                                 unsigned short* __restrict__ wt) {
    const int c  = threadIdx.x;
    const int k0 = blockIdx.x * 4;
    ushort4 o;
    o.x = f2bf(Wm[(size_t)(k0 + 0) * D + c]);
    o.y = f2bf(Wm[(size_t)(k0 + 1) * D + c]);
    o.z = f2bf(Wm[(size_t)(k0 + 2) * D + c]);
    o.w = f2bf(Wm[(size_t)(k0 + 3) * D + c]);
    *(ushort4*)(wt + (size_t)c * D + k0) = o;   // Wt[c][k0..k0+3]
}

// ---------------- K1: weighted neighbor pooling ---------------------------
__global__ __launch_bounds__(256, 8) void pool(const float* __restrict__ feat,
                                               const int*   __restrict__ nbr,
                                               const float* __restrict__ iw,
                                               unsigned short* __restrict__ aggb) {
    const int  t    = threadIdx.x;
    const int  lane = t & 63;
    const int  wq   = t >> 6;
    const long n    = (long)blockIdx.x * 4 + wq;   // one wave per node

    float ws = 0.f;
    #pragma unroll
    for (int k = 0; k < KNB; ++k) ws += iw[n * KNB + k];
    const bool  zs  = (ws == 0.f);
    const float inv = zs ? (1.f / KNB) : (1.f / ws);

    float4 p = make_float4(0.f, 0.f, 0.f, 0.f);
    #pragma unroll 1
    for (int kb = 0; kb < KNB; kb += 8) {          // 2 batches of 8 in-flight gathers
        int   idx[8];
        float w[8];
        #pragma unroll
        for (int k = 0; k < 8; ++k) {
            idx[k] = nbr[n * KNB + kb + k];
            w[k]   = iw [n * KNB + kb + k];
        }
        #pragma unroll
        for (int k = 0; k < 8; ++k) {
            const float  wk = zs ? inv : (w[k] * inv);
            const float4 f  = *(const float4*)(feat + (size_t)idx[k] * D + lane * 4);
            p.x += wk * f.x; p.y += wk * f.y; p.z += wk * f.z; p.w += wk * f.w;
        }
    }
    ushort4 o;
    o.x = f2bf(p.x); o.y = f2bf(p.y); o.z = f2bf(p.z); o.w = f2bf(p.w);
    *(ushort4*)(aggb + (size_t)n * 512 + lane * 4) = o;   // row n @ 1 KB stride
}

// ---------------- K2: bf16 MFMA GEMM + LayerNorm --------------------------
// Block = 4 waves x 16 rows = 64 rows; each wave: 16 col-tiles of 16x16x32 MFMA.
__global__ __launch_bounds__(256, 2) void gemm_ln(const unsigned short* __restrict__ aggb,
                                                  const unsigned short* __restrict__ wt,
                                                  const float* __restrict__ bias,
                                                  const float* __restrict__ gamma,
                                                  const float* __restrict__ beta,
                                                  float* __restrict__ out) {
    const int t       = threadIdx.x;
    const int lane    = t & 63;
    const int wq      = t >> 6;
    const int quad    = lane >> 4;        // k-group for A/B frags; row-group for C
    const int l15     = lane & 15;        // A row / B col within tile
    const int rowbase = blockIdx.x * 64 + wq * 16;

    // A-frag: A[m=l15][k=quad*8+j]; agg rows at 512-short (1 KB) stride
    const int arow = min(rowbase + l15, NN - 1);
    const unsigned short* aptr = aggb + (size_t)arow * 512 + quad * 8;
    // B-frag: B[k=quad*8+j][n=l15 + 16*tile] from Wt[n][k] contiguous-k
    const unsigned short* bptr = wt + (size_t)l15 * D + quad * 8;

    f32x4 acc[16];
    #pragma unroll
    for (int c = 0; c < 16; ++c) acc[c] = (f32x4){0.f, 0.f, 0.f, 0.f};

    #pragma unroll
    for (int kb = 0; kb < D; kb += 32) {
        const short8 a = *(const short8*)(aptr + kb);
        #pragma unroll
        for (int c = 0; c < 16; ++c) {
            const short8 b = *(const short8*)(bptr + (size_t)c * (16 * D) + kb);
            acc[c] = __builtin_amdgcn_mfma_f32_16x16x32_bf16(a, b, acc[c], 0, 0, 0);
        }
    }

    // Epilogue: +bias, LN over 256 cols, *gamma +beta, store fp32.
    float bv[16], gv[16], btv[16];
    #pragma unroll
    for (int c = 0; c < 16; ++c) {
        bv[c]  = bias [c * 16 + l15];
        gv[c]  = gamma[c * 16 + l15];
        btv[c] = beta [c * 16 + l15];
    }
    #pragma unroll
    for (int j = 0; j < 4; ++j) {          // C/D: row = quad*4 + j, col = c*16 + l15
        const int r = rowbase + quad * 4 + j;
        float s = 0.f, sq = 0.f;
        #pragma unroll
        for (int c = 0; c < 16; ++c) {
            const float v = acc[c][j] + bv[c];
            s += v; sq += v * v;
        }
        #pragma unroll
        for (int off = 1; off < 16; off <<= 1) {   // reduce across l15 (same quad)
            s  += __shfl_xor(s,  off, 64);
            sq += __shfl_xor(sq, off, 64);
        }
        const float mean = s * (1.f / D);
        const float var  = sq * (1.f / D) - mean * mean;   // biased (torch LN)
        const float rstd = rsqrtf(var + 1e-5f);
        if (r < NN) {
            #pragma unroll
            for (int c = 0; c < 16; ++c) {
                const float v = acc[c][j] + bv[c];
                out[(size_t)r * D + c * 16 + l15] = (v - mean) * rstd * gv[c] + btv[c];
            }
        }
    }
}

extern "C" void kernel_launch(void* const* d_in, const int* in_sizes, int n_in,
                              void* d_out, int out_size, void* d_ws, size_t ws_size,
                              hipStream_t stream) {
    const float* feat = (const float*)d_in[0];
    const int*   nbr  = (const int*)d_in[1];
    const float* iw   = (const float*)d_in[2];
    const float* Wm   = (const float*)d_in[3];
    const float* b    = (const float*)d_in[4];
    const float* g    = (const float*)d_in[5];
    const float* be   = (const float*)d_in[6];
    float*       out  = (float*)d_out;

    unsigned short* wt   = (unsigned short*)d_ws;   // 256*256*2 = 128 KB
    unsigned short* aggb = (unsigned short*)d_out;  // bf16 rows @ 1 KB stride

    convert_w<<<dim3(64),            dim3(256), 0, stream>>>(Wm, wt);
    pool     <<<dim3(NN / 4),        dim3(256), 0, stream>>>(feat, nbr, iw, aggb);
    gemm_ln  <<<dim3((NN + 63) / 64), dim3(256), 0, stream>>>(aggb, wt, b, g, be, out);
}

// Round 3
// 190.907 us; speedup vs baseline: 2.1386x; 1.4282x over previous
//
#include <hip/hip_runtime.h>

// ImportanceAggregator pipeline (all per-launch, d_ws re-poisoned each call):
//   K0 convert_w    : W[k][c] fp32 -> wtp, bf16 packed in MFMA B-frag order
//   K1 convert_feat : feat fp32 -> featb bf16 (halves pool gather bytes)
//   K2 pool         : agg[n] = sum_k w~[n,k] * featb[nbr[n,k]]  (fp32 acc, bf16 out)
//   K3 gemm_ln      : out = LN(agg @ W + b) * gamma + beta  via MFMA 16x16x32,
//                     coalesced packed-B loads + LDS-transposed float4 epilogue
// agg bf16 rows live in d_out at 1 KB stride; gemm_ln block b reads only its own
// 64 rows then overwrites exactly those byte ranges -> no cross-block hazard.

#define NN   50000
#define KNB  16
#define D    256

typedef __attribute__((ext_vector_type(8))) short short8;   // 8 x bf16 (4 VGPRs)
typedef __attribute__((ext_vector_type(4))) float f32x4;

static __device__ __forceinline__ unsigned short f2bf(float x) {
    unsigned int u = __float_as_uint(x);
    return (unsigned short)((u + 0x7FFFu + ((u >> 16) & 1u)) >> 16);  // RNE
}
static __device__ __forceinline__ float bf2f(unsigned short h) {
    return __uint_as_float((unsigned int)h << 16);
}

// ---------------- K0: W -> bf16 packed in B-fragment order ----------------
// frag g = (c*8 + kb32)*64 + lane holds B[k = quad*8 + kb32*32 + j][n = c*16 + l15]
__global__ __launch_bounds__(256) void convert_w(const float* __restrict__ Wm,
                                                 unsigned short* __restrict__ wtp) {
    const int g    = blockIdx.x * 256 + threadIdx.x;   // 0..8191
    const int lane = g & 63;
    const int kb32 = (g >> 6) & 7;
    const int c    = g >> 9;
    const int n    = c * 16 + (lane & 15);
    const int k0   = kb32 * 32 + (lane >> 4) * 8;
    short8 v;
    #pragma unroll
    for (int j = 0; j < 8; ++j) v[j] = (short)f2bf(Wm[(size_t)(k0 + j) * D + n]);
    *(short8*)(wtp + (size_t)g * 8) = v;               // 16 B/thread, coalesced
}

// ---------------- K1: features fp32 -> bf16 -------------------------------
__global__ __launch_bounds__(256) void convert_feat(const float* __restrict__ feat,
                                                    unsigned short* __restrict__ featb) {
    const size_t g = (size_t)blockIdx.x * 256 + threadIdx.x;  // 1.6M threads, 8 elem each
    const float4 a = *(const float4*)(feat + g * 8);
    const float4 b = *(const float4*)(feat + g * 8 + 4);
    short8 o;
    o[0] = (short)f2bf(a.x); o[1] = (short)f2bf(a.y);
    o[2] = (short)f2bf(a.z); o[3] = (short)f2bf(a.w);
    o[4] = (short)f2bf(b.x); o[5] = (short)f2bf(b.y);
    o[6] = (short)f2bf(b.z); o[7] = (short)f2bf(b.w);
    *(short8*)(featb + g * 8) = o;
}

// ---------------- K2: weighted neighbor pooling (bf16 gathers) ------------
__global__ __launch_bounds__(256, 8) void pool_b(const unsigned short* __restrict__ featb,
                                                 const int*   __restrict__ nbr,
                                                 const float* __restrict__ iw,
                                                 unsigned short* __restrict__ aggb) {
    const int  t    = threadIdx.x;
    const int  lane = t & 63;
    const int  wq   = t >> 6;
    const long n    = (long)blockIdx.x * 4 + wq;   // one wave per node

    float ws = 0.f;
    #pragma unroll
    for (int k = 0; k < KNB; ++k) ws += iw[n * KNB + k];
    const bool  zs  = (ws == 0.f);
    const float inv = zs ? (1.f / KNB) : (1.f / ws);

    float4 p = make_float4(0.f, 0.f, 0.f, 0.f);
    #pragma unroll 1
    for (int kb = 0; kb < KNB; kb += 8) {          // 8 gathers in flight per batch
        int   idx[8];
        float w[8];
        #pragma unroll
        for (int k = 0; k < 8; ++k) {
            idx[k] = nbr[n * KNB + kb + k];
            w[k]   = iw [n * KNB + kb + k];
        }
        #pragma unroll
        for (int k = 0; k < 8; ++k) {
            const float   wk = zs ? inv : (w[k] * inv);
            const ushort4 u  = *(const ushort4*)(featb + (size_t)idx[k] * D + lane * 4);
            p.x += wk * bf2f(u.x); p.y += wk * bf2f(u.y);
            p.z += wk * bf2f(u.z); p.w += wk * bf2f(u.w);
        }
    }
    ushort4 o;
    o.x = f2bf(p.x); o.y = f2bf(p.y); o.z = f2bf(p.z); o.w = f2bf(p.w);
    *(ushort4*)(aggb + (size_t)n * 512 + lane * 4) = o;   // row n @ 1 KB stride
}

// Fallback (ws too small for featb): fp32 gathers, as Round 2.
__global__ __launch_bounds__(256, 8) void pool_f(const float* __restrict__ feat,
                                                 const int*   __restrict__ nbr,
                                                 const float* __restrict__ iw,
                                                 unsigned short* __restrict__ aggb) {
    const int  t    = threadIdx.x;
    const int  lane = t & 63;
    const int  wq   = t >> 6;
    const long n    = (long)blockIdx.x * 4 + wq;
    float ws = 0.f;
    #pragma unroll
    for (int k = 0; k < KNB; ++k) ws += iw[n * KNB + k];
    const bool  zs  = (ws == 0.f);
    const float inv = zs ? (1.f / KNB) : (1.f / ws);
    float4 p = make_float4(0.f, 0.f, 0.f, 0.f);
    #pragma unroll 1
    for (int kb = 0; kb < KNB; kb += 8) {
        int idx[8]; float w[8];
        #pragma unroll
        for (int k = 0; k < 8; ++k) { idx[k] = nbr[n*KNB+kb+k]; w[k] = iw[n*KNB+kb+k]; }
        #pragma unroll
        for (int k = 0; k < 8; ++k) {
            const float  wk = zs ? inv : (w[k] * inv);
            const float4 f  = *(const float4*)(feat + (size_t)idx[k] * D + lane * 4);
            p.x += wk*f.x; p.y += wk*f.y; p.z += wk*f.z; p.w += wk*f.w;
        }
    }
    ushort4 o;
    o.x = f2bf(p.x); o.y = f2bf(p.y); o.z = f2bf(p.z); o.w = f2bf(p.w);
    *(ushort4*)(aggb + (size_t)n * 512 + lane * 4) = o;
}

// ---------------- K3: bf16 MFMA GEMM + LayerNorm --------------------------
__global__ __launch_bounds__(256, 2) void gemm_ln(const unsigned short* __restrict__ aggb,
                                                  const unsigned short* __restrict__ wtp,
                                                  const float* __restrict__ bias,
                                                  const float* __restrict__ gamma,
                                                  const float* __restrict__ beta,
                                                  float* __restrict__ out) {
    __shared__ float sO[64][257];                   // padded: conflict-free transpose

    const int t       = threadIdx.x;
    const int lane    = t & 63;
    const int wq      = t >> 6;
    const int quad    = lane >> 4;
    const int l15     = lane & 15;
    const int rowbase = blockIdx.x * 64 + wq * 16;

    const int arow = min(rowbase + l15, NN - 1);
    const unsigned short* aptr = aggb + (size_t)arow * 512 + quad * 8;
    const short8* wv = (const short8*)wtp;

    f32x4 acc[16];
    #pragma unroll
    for (int c = 0; c < 16; ++c) acc[c] = (f32x4){0.f, 0.f, 0.f, 0.f};

    #pragma unroll
    for (int kb32 = 0; kb32 < 8; ++kb32) {
        const short8 a = *(const short8*)(aptr + kb32 * 32);
        #pragma unroll
        for (int c = 0; c < 16; ++c) {
            const short8 b = wv[(size_t)(c * 8 + kb32) * 64 + lane];  // dense 4 KB/instr
            acc[c] = __builtin_amdgcn_mfma_f32_16x16x32_bf16(a, b, acc[c], 0, 0, 0);
        }
    }

    float bv[16], gv[16], btv[16];
    #pragma unroll
    for (int c = 0; c < 16; ++c) {
        bv[c]  = bias [c * 16 + l15];
        gv[c]  = gamma[c * 16 + l15];
        btv[c] = beta [c * 16 + l15];
    }
    #pragma unroll
    for (int j = 0; j < 4; ++j) {       // C/D: row = quad*4 + j, col = c*16 + l15
        float s = 0.f, sq = 0.f;
        #pragma unroll
        for (int c = 0; c < 16; ++c) {
            const float v = acc[c][j] + bv[c];
            s += v; sq += v * v;
        }
        #pragma unroll
        for (int off = 1; off < 16; off <<= 1) {   // reduce across l15 (same quad)
            s  += __shfl_xor(s,  off, 64);
            sq += __shfl_xor(sq, off, 64);
        }
        const float mean = s * (1.f / D);
        const float var  = sq * (1.f / D) - mean * mean;   // biased (torch LN)
        const float rstd = rsqrtf(var + 1e-5f);
        const int   lrow = wq * 16 + quad * 4 + j;
        #pragma unroll
        for (int c = 0; c < 16; ++c) {
            const float v = acc[c][j] + bv[c];
            sO[lrow][c * 16 + l15] = (v - mean) * rstd * gv[c] + btv[c];
        }
    }
    __syncthreads();

    #pragma unroll
    for (int p = 0; p < 16; ++p) {      // coalesced float4 stores, 1 KB/wave-instr
        const int row = p * 4 + wq;
        const int r   = blockIdx.x * 64 + row;
        if (r < NN)
            *(float4*)(out + (size_t)r * D + lane * 4) = *(float4*)&sO[row][lane * 4];
    }
}

extern "C" void kernel_launch(void* const* d_in, const int* in_sizes, int n_in,
                              void* d_out, int out_size, void* d_ws, size_t ws_size,
                              hipStream_t stream) {
    const float* feat = (const float*)d_in[0];
    const int*   nbr  = (const int*)d_in[1];
    const float* iw   = (const float*)d_in[2];
    const float* Wm   = (const float*)d_in[3];
    const float* b    = (const float*)d_in[4];
    const float* g    = (const float*)d_in[5];
    const float* be   = (const float*)d_in[6];
    float*       out  = (float*)d_out;

    unsigned short* wtp   = (unsigned short*)d_ws;                  // 128 KB
    unsigned short* featb = (unsigned short*)((char*)d_ws + 131072); // 25.6 MB
    unsigned short* aggb  = (unsigned short*)d_out;                 // bf16 rows @ 1 KB

    const size_t need = 131072 + (size_t)NN * D * 2;

    convert_w<<<dim3(32), dim3(256), 0, stream>>>(Wm, wtp);
    if (ws_size >= need) {
        convert_feat<<<dim3(6250),    dim3(256), 0, stream>>>(feat, featb);
        pool_b      <<<dim3(NN / 4),  dim3(256), 0, stream>>>(featb, nbr, iw, aggb);
    } else {
        pool_f      <<<dim3(NN / 4),  dim3(256), 0, stream>>>(feat, nbr, iw, aggb);
    }
    gemm_ln<<<dim3((NN + 63) / 64), dim3(256), 0, stream>>>(aggb, wtp, b, g, be, out);
}